// Round 10
// baseline (88.990 us; speedup 1.0000x reference)
//
#include <hip/hip_runtime.h>
#include <math.h>

namespace {
constexpr int P = 4096, O = 32, H = 26, V = 48;
constexpr int GPITCH = 28;            // Gram row stride (floats); 112B rows, 16B-aligned
constexpr float EPSV = 1e-4f;         // strict < EPSV == numpy's (f32 <= 1e-4 f64)
}

// One thread per (point p, object o).
// Gram trick: Appb[h][j] = s_j - s_h * G[h][j], G = A A^T in LDS.
// s_j keeps the reference's exact rounding (argmax/max_vals/is_neg exact).
// t_j folded to one FMA; psq = s_h^2 * G[h][h] (ulp-level drift, selection
// ties only); sqrt once per pass (correctly-rounded sqrt is monotone).
// Edge pass FMA-factored with inv_den / -(v1.e)*inv precomputed at stage.
__global__ __launch_bounds__(256) void zono_kernel(
    const float* __restrict__ point,   // [P][3]
    const float* __restrict__ hA,      // [O][H][3]
    const float* __restrict__ hb,      // [O][H]
    const float* __restrict__ v1g,     // [O][V][3]
    const float* __restrict__ v2g,     // [O][V][3]
    float* __restrict__ dist_out,      // [P][O]
    float* __restrict__ grad_out)      // [P][O][3]
{
    __shared__ float4 sAb[H];            // {a0,a1,a2,b}
    __shared__ float  sG[H][GPITCH];     // Gram a_h . a_j
    __shared__ float4 sV1[V];            // {v1_0,v1_1,v1_2, inv_den}
    __shared__ float4 sE[V];             // {e0,e1,e2, -(v1.e)*inv_den}

    const int o   = blockIdx.y;
    const int tid = threadIdx.x;

    if (tid < H) {
        const float* a = hA + (o * H + tid) * 3;
        sAb[tid] = make_float4(a[0], a[1], a[2], hb[o * H + tid]);
    } else if (tid >= 32 && tid < 32 + V) {
        const int v = tid - 32;
        const float* A1 = v1g + (o * V + v) * 3;
        const float* A2 = v2g + (o * V + v) * 3;
        const float x0 = A1[0], x1 = A1[1], x2 = A1[2];
        const float e0 = __fsub_rn(A2[0], x0);
        const float e1 = __fsub_rn(A2[1], x1);
        const float e2 = __fsub_rn(A2[2], x2);
        const float den = __fadd_rn(__fadd_rn(__fmul_rn(e0, e0), __fmul_rn(e1, e1)),
                                    __fmul_rn(e2, e2));
        const float inv = __fdiv_rn(1.f, den);
        const float cv  = __fadd_rn(__fadd_rn(__fmul_rn(x0, e0), __fmul_rn(x1, e1)),
                                    __fmul_rn(x2, e2));
        const float nci = -__fmul_rn(cv, inv);
        sV1[v] = make_float4(x0, x1, x2, inv);
        sE[v]  = make_float4(e0, e1, e2, nci);
    }
    __syncthreads();

    // Build Gram table.
    for (int e = tid; e < H * H; e += 256) {
        const int h = e / H;
        const int j = e - h * H;
        const float4 A = sAb[h];
        const float4 B = sAb[j];
        sG[h][j] = __fadd_rn(__fadd_rn(__fmul_rn(A.x, B.x), __fmul_rn(A.y, B.y)),
                             __fmul_rn(A.z, B.z));
    }
    __syncthreads();

    const int p = blockIdx.x * blockDim.x + tid;
    const float p0 = point[p * 3 + 0];
    const float p1 = point[p * 3 + 1];
    const float p2 = point[p * 3 + 2];

    // ---- s_j (exact reference rounding) + argmax; is_neg == (maxv <= 0) ----
    float s[H];                          // compile-time indexed only (unrolled)
    float maxv = -INFINITY; int maxi = 0;
    #pragma unroll
    for (int j = 0; j < H; ++j) {
        const float4 ab = sAb[j];
        s[j] = __fsub_rn(
            __fadd_rn(__fadd_rn(__fmul_rn(p0, ab.x), __fmul_rn(p1, ab.y)),
                      __fmul_rn(p2, ab.z)),
            ab.w);
        if (s[j] > maxv) { maxv = s[j]; maxi = j; }    // first argmax
    }
    const bool is_neg = (maxv <= 0.f);

    // ---- face pass: t_j = fma(-sh, G[h][j], s_j); psq = sh^2 * G[h][h] ----
    float minpsq = INFINITY; int mini = 0;
    #pragma unroll
    for (int h = 0; h < H; ++h) {
        const float sh = s[h];
        float m0 = -INFINITY, m1 = -INFINITY, m2 = -INFINITY, m3 = -INFINITY;
        const float4* gRow = reinterpret_cast<const float4*>(&sG[h][0]);
        #pragma unroll
        for (int q = 0; q < 6; ++q) {                    // j = 0..23
            const float4 g = gRow[q];
            m0 = fmaxf(m0, __builtin_fmaf(-sh, g.x, s[4 * q + 0]));
            m1 = fmaxf(m1, __builtin_fmaf(-sh, g.y, s[4 * q + 1]));
            m2 = fmaxf(m2, __builtin_fmaf(-sh, g.z, s[4 * q + 2]));
            m3 = fmaxf(m3, __builtin_fmaf(-sh, g.w, s[4 * q + 3]));
        }
        {
            const float2 g = *reinterpret_cast<const float2*>(&sG[h][24]);
            m0 = fmaxf(m0, __builtin_fmaf(-sh, g.x, s[24]));
            m1 = fmaxf(m1, __builtin_fmaf(-sh, g.y, s[25]));
        }
        const bool onz = (fmaxf(fmaxf(m0, m1), fmaxf(m2, m3)) < EPSV);

        const float psq = __fmul_rn(__fmul_rn(sh, sh), sG[h][h]);
        if (onz && psq < minpsq) { minpsq = psq; mini = h; }  // first argmin
    }
    const float minperp = __fsqrt_rn(minpsq);   // monotone: == min of sqrts

    // ---- edge pass: th = fma(p.e, inv, nci); track (ts, idx), q later ----
    float minesq = INFINITY; int midx = 0; float tsm = 0.f;
    #pragma unroll 2
    for (int v = 0; v < V; ++v) {
        const float4 V1 = sV1[v];
        const float4 E  = sE[v];
        const float dpe = __builtin_fmaf(p0, E.x,
                          __builtin_fmaf(p1, E.y, __fmul_rn(p2, E.z)));
        const float th = __builtin_fmaf(dpe, V1.w, E.w);
        const float ts = __builtin_amdgcn_fmed3f(th, 0.f, 1.f);
        const float g0 = __fsub_rn(p0, __builtin_fmaf(ts, E.x, V1.x));
        const float g1 = __fsub_rn(p1, __builtin_fmaf(ts, E.y, V1.y));
        const float g2 = __fsub_rn(p2, __builtin_fmaf(ts, E.z, V1.z));
        const float esq = __builtin_fmaf(g0, g0,
                          __builtin_fmaf(g1, g1, __fmul_rn(g2, g2)));
        if (esq < minesq) { minesq = esq; midx = v; tsm = ts; }
    }
    const float mine = __fsqrt_rn(minesq);      // monotone: == min of sqrts

    // Recompute winner's closest point (deterministic, bitwise equal).
    const float4 V1w = sV1[midx];
    const float4 Ew  = sE[midx];
    const float vm0 = __builtin_fmaf(tsm, Ew.x, V1w.x);
    const float vm1 = __builtin_fmaf(tsm, Ew.y, V1w.y);
    const float vm2 = __builtin_fmaf(tsm, Ew.z, V1w.z);

    // ---- select ----
    const int   fidx = is_neg ? maxi : mini;
    const float4 ga  = sAb[fidx];
    float dist = is_neg ? maxv : minperp;
    float g0 = ga.x, g1 = ga.y, g2 = ga.z;
    if (!is_neg && (mine < dist)) {
        dist = mine;
        g0 = __fdiv_rn(__fsub_rn(p0, vm0), mine);
        g1 = __fdiv_rn(__fsub_rn(p1, vm1), mine);
        g2 = __fdiv_rn(__fsub_rn(p2, vm2), mine);
    }

    const int idx = p * O + o;
    dist_out[idx] = dist;
    grad_out[idx * 3 + 0] = g0;
    grad_out[idx * 3 + 1] = g1;
    grad_out[idx * 3 + 2] = g2;
}

extern "C" void kernel_launch(void* const* d_in, const int* in_sizes, int n_in,
                              void* d_out, int out_size, void* d_ws, size_t ws_size,
                              hipStream_t stream) {
    const float* point = (const float*)d_in[0];
    const float* hA    = (const float*)d_in[1];
    const float* hb    = (const float*)d_in[2];
    const float* v1    = (const float*)d_in[3];
    const float* v2    = (const float*)d_in[4];
    float* out = (float*)d_out;

    dim3 grid(P / 256, O);
    zono_kernel<<<grid, dim3(256), 0, stream>>>(point, hA, hb, v1, v2,
                                                out, out + P * O);
}

// Round 11
// 18.248 us; speedup vs baseline: 4.8768x; 4.8768x over previous
//
#include <hip/hip_runtime.h>
#include <math.h>

namespace {
constexpr int P = 4096, O = 32, H = 26, V = 48;
constexpr int GPITCH = 28;            // Gram row stride (floats); 112B rows, 16B-aligned
constexpr float EPSV = 1e-4f;         // strict < EPSV == numpy's (f32 <= 1e-4 f64)
}

// One thread per (point p, object o).
// Gram trick: Appb[h][j] = s_j - s_h * G[h][j], G = A A^T in LDS.
// s_j keeps the reference's exact rounding (argmax/max_vals/is_neg exact).
// t_j folded to one FMA; psq = s_h^2 * G[h][h]; sqrt once per pass
// (correctly-rounded sqrt is monotone => min-of-sqrt == sqrt-of-min bitwise).
// Edge pass FMA-factored with inv_den / -(v1.e)*inv precomputed at stage.
// Face loop stays ROLLED: full unroll (R10) exploded to 256 VGPR + 177MB
// scratch spill traffic (4.4x slowdown). sh is recomputed from LDS per h with
// the reference's exact rounding (== s[h] bitwise).
__global__ __launch_bounds__(256) void zono_kernel(
    const float* __restrict__ point,   // [P][3]
    const float* __restrict__ hA,      // [O][H][3]
    const float* __restrict__ hb,      // [O][H]
    const float* __restrict__ v1g,     // [O][V][3]
    const float* __restrict__ v2g,     // [O][V][3]
    float* __restrict__ dist_out,      // [P][O]
    float* __restrict__ grad_out)      // [P][O][3]
{
    __shared__ float4 sAb[H];            // {a0,a1,a2,b}
    __shared__ float  sG[H][GPITCH];     // Gram a_h . a_j
    __shared__ float4 sV1[V];            // {v1_0,v1_1,v1_2, inv_den}
    __shared__ float4 sE[V];             // {e0,e1,e2, -(v1.e)*inv_den}

    const int o   = blockIdx.y;
    const int tid = threadIdx.x;

    if (tid < H) {
        const float* a = hA + (o * H + tid) * 3;
        sAb[tid] = make_float4(a[0], a[1], a[2], hb[o * H + tid]);
    } else if (tid >= 32 && tid < 32 + V) {
        const int v = tid - 32;
        const float* A1 = v1g + (o * V + v) * 3;
        const float* A2 = v2g + (o * V + v) * 3;
        const float x0 = A1[0], x1 = A1[1], x2 = A1[2];
        const float e0 = __fsub_rn(A2[0], x0);
        const float e1 = __fsub_rn(A2[1], x1);
        const float e2 = __fsub_rn(A2[2], x2);
        const float den = __fadd_rn(__fadd_rn(__fmul_rn(e0, e0), __fmul_rn(e1, e1)),
                                    __fmul_rn(e2, e2));
        const float inv = __fdiv_rn(1.f, den);
        const float cv  = __fadd_rn(__fadd_rn(__fmul_rn(x0, e0), __fmul_rn(x1, e1)),
                                    __fmul_rn(x2, e2));
        const float nci = -__fmul_rn(cv, inv);
        sV1[v] = make_float4(x0, x1, x2, inv);
        sE[v]  = make_float4(e0, e1, e2, nci);
    }
    __syncthreads();

    // Build Gram table.
    for (int e = tid; e < H * H; e += 256) {
        const int h = e / H;
        const int j = e - h * H;
        const float4 A = sAb[h];
        const float4 B = sAb[j];
        sG[h][j] = __fadd_rn(__fadd_rn(__fmul_rn(A.x, B.x), __fmul_rn(A.y, B.y)),
                             __fmul_rn(A.z, B.z));
    }
    __syncthreads();

    const int p = blockIdx.x * blockDim.x + tid;
    const float p0 = point[p * 3 + 0];
    const float p1 = point[p * 3 + 1];
    const float p2 = point[p * 3 + 2];

    // ---- s_j (exact reference rounding) + argmax; is_neg == (maxv <= 0) ----
    float s[H];                          // compile-time indexed only
    float maxv = -INFINITY; int maxi = 0;
    #pragma unroll
    for (int j = 0; j < H; ++j) {
        const float4 ab = sAb[j];
        s[j] = __fsub_rn(
            __fadd_rn(__fadd_rn(__fmul_rn(p0, ab.x), __fmul_rn(p1, ab.y)),
                      __fmul_rn(p2, ab.z)),
            ab.w);
        if (s[j] > maxv) { maxv = s[j]; maxi = j; }    // first argmax
    }
    const bool is_neg = (maxv <= 0.f);

    // ---- face pass (ROLLED): t_j = fma(-sh, G[h][j], s_j) ----
    float minpsq = INFINITY; int mini = 0;
    for (int h = 0; h < H; ++h) {
        const float4 ab = sAb[h];                       // broadcast LDS read
        const float sh = __fsub_rn(                     // == s[h] bitwise
            __fadd_rn(__fadd_rn(__fmul_rn(p0, ab.x), __fmul_rn(p1, ab.y)),
                      __fmul_rn(p2, ab.z)),
            ab.w);

        float m0 = -INFINITY, m1 = -INFINITY, m2 = -INFINITY, m3 = -INFINITY;
        const float4* gRow = reinterpret_cast<const float4*>(&sG[h][0]);
        #pragma unroll
        for (int q = 0; q < 6; ++q) {                    // j = 0..23
            const float4 g = gRow[q];
            m0 = fmaxf(m0, __builtin_fmaf(-sh, g.x, s[4 * q + 0]));
            m1 = fmaxf(m1, __builtin_fmaf(-sh, g.y, s[4 * q + 1]));
            m2 = fmaxf(m2, __builtin_fmaf(-sh, g.z, s[4 * q + 2]));
            m3 = fmaxf(m3, __builtin_fmaf(-sh, g.w, s[4 * q + 3]));
        }
        {
            const float2 g = *reinterpret_cast<const float2*>(&sG[h][24]);
            m0 = fmaxf(m0, __builtin_fmaf(-sh, g.x, s[24]));
            m1 = fmaxf(m1, __builtin_fmaf(-sh, g.y, s[25]));
        }
        const bool onz = (fmaxf(fmaxf(m0, m1), fmaxf(m2, m3)) < EPSV);

        const float psq = __fmul_rn(__fmul_rn(sh, sh), sG[h][h]);
        if (onz && psq < minpsq) { minpsq = psq; mini = h; }  // first argmin
    }
    const float minperp = __fsqrt_rn(minpsq);   // monotone: == min of sqrts

    // ---- edge pass: th = fma(p.e, inv, nci); track (ts, idx), q later ----
    float minesq = INFINITY; int midx = 0; float tsm = 0.f;
    #pragma unroll 2
    for (int v = 0; v < V; ++v) {
        const float4 V1 = sV1[v];
        const float4 E  = sE[v];
        const float dpe = __builtin_fmaf(p0, E.x,
                          __builtin_fmaf(p1, E.y, __fmul_rn(p2, E.z)));
        const float th = __builtin_fmaf(dpe, V1.w, E.w);
        const float ts = __builtin_amdgcn_fmed3f(th, 0.f, 1.f);
        const float g0 = __fsub_rn(p0, __builtin_fmaf(ts, E.x, V1.x));
        const float g1 = __fsub_rn(p1, __builtin_fmaf(ts, E.y, V1.y));
        const float g2 = __fsub_rn(p2, __builtin_fmaf(ts, E.z, V1.z));
        const float esq = __builtin_fmaf(g0, g0,
                          __builtin_fmaf(g1, g1, __fmul_rn(g2, g2)));
        if (esq < minesq) { minesq = esq; midx = v; tsm = ts; }
    }
    const float mine = __fsqrt_rn(minesq);      // monotone: == min of sqrts

    // Recompute winner's closest point (deterministic, bitwise equal).
    const float4 V1w = sV1[midx];
    const float4 Ew  = sE[midx];
    const float vm0 = __builtin_fmaf(tsm, Ew.x, V1w.x);
    const float vm1 = __builtin_fmaf(tsm, Ew.y, V1w.y);
    const float vm2 = __builtin_fmaf(tsm, Ew.z, V1w.z);

    // ---- select ----
    const int   fidx = is_neg ? maxi : mini;
    const float4 ga  = sAb[fidx];
    float dist = is_neg ? maxv : minperp;
    float g0 = ga.x, g1 = ga.y, g2 = ga.z;
    if (!is_neg && (mine < dist)) {
        dist = mine;
        g0 = __fdiv_rn(__fsub_rn(p0, vm0), mine);
        g1 = __fdiv_rn(__fsub_rn(p1, vm1), mine);
        g2 = __fdiv_rn(__fsub_rn(p2, vm2), mine);
    }

    const int idx = p * O + o;
    dist_out[idx] = dist;
    grad_out[idx * 3 + 0] = g0;
    grad_out[idx * 3 + 1] = g1;
    grad_out[idx * 3 + 2] = g2;
}

extern "C" void kernel_launch(void* const* d_in, const int* in_sizes, int n_in,
                              void* d_out, int out_size, void* d_ws, size_t ws_size,
                              hipStream_t stream) {
    const float* point = (const float*)d_in[0];
    const float* hA    = (const float*)d_in[1];
    const float* hb    = (const float*)d_in[2];
    const float* v1    = (const float*)d_in[3];
    const float* v2    = (const float*)d_in[4];
    float* out = (float*)d_out;

    dim3 grid(P / 256, O);
    zono_kernel<<<grid, dim3(256), 0, stream>>>(point, hA, hb, v1, v2,
                                                out, out + P * O);
}